// Round 1
// baseline (256.257 us; speedup 1.0000x reference)
//
#include <hip/hip_runtime.h>
#include <math.h>

#define L_SEQ 4096
#define C_DIM 256
#define H_HEADS 8
#define K_MAX 64
#define D_HEAD 32
#define HALF_W 32
#define N_OFF 65          // 2*HALF_W + 1
#define HK 512            // H_HEADS * K_MAX

__device__ __forceinline__ float sigmoidf_(float x) { return 1.0f / (1.0f + expf(-x)); }

// ---------------- Kernel 1: window-size & center-offset projections ----------------
// One 64-thread wave per row l. 16 dot products of length 256, butterfly-reduced.
__global__ void proj_small_kernel(const float* __restrict__ x,
                                  const float* __restrict__ ww, const float* __restrict__ wb,
                                  const float* __restrict__ wg,
                                  const float* __restrict__ ow, const float* __restrict__ ob,
                                  const float* __restrict__ og,
                                  float* __restrict__ wsizes, float* __restrict__ offs) {
    const int l = blockIdx.x;
    const int lane = threadIdx.x;  // 0..63
    const float* xr = x + l * C_DIM;

    float accw[H_HEADS], acco[H_HEADS];
#pragma unroll
    for (int h = 0; h < H_HEADS; ++h) { accw[h] = 0.0f; acco[h] = 0.0f; }

#pragma unroll
    for (int i = 0; i < C_DIM / 64; ++i) {
        const int c = lane + i * 64;
        const float xv = xr[c];
        const float* wwc = ww + c * H_HEADS;
        const float* owc = ow + c * H_HEADS;
#pragma unroll
        for (int h = 0; h < H_HEADS; ++h) {
            accw[h] = fmaf(xv, wwc[h], accw[h]);
            acco[h] = fmaf(xv, owc[h], acco[h]);
        }
    }
    // butterfly reduce across the 64-lane wave
#pragma unroll
    for (int off = 32; off > 0; off >>= 1) {
#pragma unroll
        for (int h = 0; h < H_HEADS; ++h) {
            accw[h] += __shfl_xor(accw[h], off);
            acco[h] += __shfl_xor(acco[h], off);
        }
    }
    if (lane == 0) {
        float zw[H_HEADS], zo[H_HEADS];
        float ssw = 0.0f, sso = 0.0f;
#pragma unroll
        for (int h = 0; h < H_HEADS; ++h) {
            zw[h] = accw[h] + wb[h];
            zo[h] = acco[h] + ob[h];
            ssw += zw[h] * zw[h];
            sso += zo[h] * zo[h];
        }
        const float rw = rsqrtf(ssw / (float)H_HEADS + 1e-6f);
        const float ro = rsqrtf(sso / (float)H_HEADS + 1e-6f);
#pragma unroll
        for (int h = 0; h < H_HEADS; ++h) {
            const float nw = wg[h] * zw[h] * rw;
            const float no = og[h] * zo[h] * ro;
            wsizes[l * H_HEADS + h] = 1.0f + sigmoidf_(nw) * (64.0f - 1.0f);  // MIN_WINDOW + raw*(max_window-MIN)
            offs[l * H_HEADS + h]   = tanhf(no) * 64.0f;                       // * max_offset
        }
    }
}

// ---------------- Kernel 2: kernel-weight projection (x @ [256,512] -> rmsnorm(512) -> silu) ----------------
// One 256-thread block per row l; each thread owns 2 output columns.
__global__ void proj_kernelw_kernel(const float* __restrict__ x, const float* __restrict__ kw_w,
                                    const float* __restrict__ kb, const float* __restrict__ kg,
                                    float* __restrict__ kw_out) {
    const int l = blockIdx.x;
    const int j = threadIdx.x;  // 0..255
    __shared__ float xs[C_DIM];
    __shared__ float red[256];
    __shared__ float rs_s;

    xs[j] = x[l * C_DIM + j];
    __syncthreads();

    float acc0 = 0.0f, acc1 = 0.0f;
    for (int c = 0; c < C_DIM; ++c) {
        const float xv = xs[c];
        acc0 = fmaf(xv, kw_w[c * HK + j], acc0);
        acc1 = fmaf(xv, kw_w[c * HK + j + 256], acc1);
    }
    const float z0 = acc0 + kb[j];
    const float z1 = acc1 + kb[j + 256];

    red[j] = z0 * z0 + z1 * z1;
    __syncthreads();
    for (int s = 128; s > 0; s >>= 1) {
        if (j < s) red[j] += red[j + s];
        __syncthreads();
    }
    if (j == 0) rs_s = rsqrtf(red[0] / (float)HK + 1e-6f);
    __syncthreads();
    const float rs = rs_s;

    const float n0 = kg[j] * z0 * rs;
    const float n1 = kg[j + 256] * z1 * rs;
    kw_out[l * HK + j]       = n0 * sigmoidf_(n0);
    kw_out[l * HK + j + 256] = n1 * sigmoidf_(n1);
}

// ---------------- Kernel 3/5: generic [l,256] = A[l,:] @ W[256,256] (+bias) (optional silu) ----------------
template <bool SILU, bool BIAS>
__global__ void gemm256_kernel(const float* __restrict__ A, const float* __restrict__ W,
                               const float* __restrict__ b, float* __restrict__ out) {
    const int l = blockIdx.x;
    const int j = threadIdx.x;  // 0..255
    __shared__ float xs[C_DIM];
    xs[j] = A[l * C_DIM + j];
    __syncthreads();
    float acc = 0.0f;
    for (int c = 0; c < C_DIM; ++c) acc = fmaf(xs[c], W[c * C_DIM + j], acc);
    if (BIAS) acc += b[j];
    if (SILU) acc = acc * sigmoidf_(acc);
    out[l * C_DIM + j] = acc;
}

// ---------------- Kernel 4: adaptive local conv ----------------
// One 256-thread block per row l. Stage 1: 8x65 attention taps into LDS.
// Stage 2: per-head denominators. Stage 3: thread (h,d) accumulates over N taps.
__global__ void conv_kernel(const float* __restrict__ wsizes, const float* __restrict__ offs,
                            const float* __restrict__ kw, const float* __restrict__ v,
                            float* __restrict__ out) {
    const int l = blockIdx.x;
    const int tid = threadIdx.x;

    __shared__ float attn[H_HEADS][N_OFF];
    __shared__ int   pfl[H_HEADS][N_OFF];
    __shared__ float frac[H_HEADS][N_OFF];
    __shared__ float inv_denom[H_HEADS];

    for (int t = tid; t < H_HEADS * N_OFF; t += 256) {
        const int h = t / N_OFF;
        const int n = t - h * N_OFF;
        const float ws  = wsizes[l * H_HEADS + h];
        const float off = offs[l * H_HEADS + h];
        const float local = (float)(n - HALF_W);
        const float neighbor = (float)l + off + local;
        const bool valid = (neighbor >= 0.0f) && (neighbor < (float)L_SEQ);
        const float nc = fminf(fmaxf(neighbor, 0.0f), (float)(L_SEQ - 1));

        const float rel = fabsf(local) / (ws * 0.5f + 1e-6f);
        const float mask = sigmoidf_(5.0f * (1.0f - rel)) * (valid ? 1.0f : 0.0f);

        const float kidx = fminf(rel, 1.0f) * (float)(K_MAX - 1);
        int ifl = (int)kidx;                 // kidx >= 0, trunc == floor
        ifl = min(ifl, K_MAX - 2);
        const float wce = kidx - (float)ifl;
        const float kf = kw[l * HK + h * K_MAX + ifl];
        const float kc = kw[l * HK + h * K_MAX + ifl + 1];
        attn[h][n] = (kf * (1.0f - wce) + kc * wce) * mask;

        int p = (int)floorf(nc);
        p = min(max(p, 0), L_SEQ - 1);
        pfl[h][n] = p;
        frac[h][n] = nc - (float)p;
    }
    __syncthreads();

    if (tid < H_HEADS) {
        float s = 0.0f;
        for (int n = 0; n < N_OFF; ++n) s += attn[tid][n];
        inv_denom[tid] = 1.0f / (s + 1e-6f);
    }
    __syncthreads();

    const int h = tid >> 5;   // 0..7
    const int d = tid & 31;   // 0..31
    float acc = 0.0f;
    for (int n = 0; n < N_OFF; ++n) {
        const float a = attn[h][n];
        const int   p = pfl[h][n];
        const float f = frac[h][n];
        const int  pc = min(p + 1, L_SEQ - 1);
        const float vf = v[p * C_DIM + h * D_HEAD + d];
        const float vc = v[pc * C_DIM + h * D_HEAD + d];
        acc = fmaf(a, vf + f * (vc - vf), acc);  // a * (vf*(1-f) + vc*f)
    }
    out[l * C_DIM + h * D_HEAD + d] = acc * inv_denom[h];
}

extern "C" void kernel_launch(void* const* d_in, const int* in_sizes, int n_in,
                              void* d_out, int out_size, void* d_ws, size_t ws_size,
                              hipStream_t stream) {
    const float* x    = (const float*)d_in[0];
    const float* ww   = (const float*)d_in[1];
    const float* wb   = (const float*)d_in[2];
    const float* wg   = (const float*)d_in[3];
    const float* ow   = (const float*)d_in[4];
    const float* ob   = (const float*)d_in[5];
    const float* og   = (const float*)d_in[6];
    const float* kw_w = (const float*)d_in[7];
    const float* kb   = (const float*)d_in[8];
    const float* kg   = (const float*)d_in[9];
    const float* vw   = (const float*)d_in[10];
    const float* vb   = (const float*)d_in[11];
    const float* outw = (const float*)d_in[12];
    float* y = (float*)d_out;

    float* ws_f    = (float*)d_ws;
    float* wsizes  = ws_f;                       // L*H
    float* offs    = wsizes + L_SEQ * H_HEADS;   // L*H
    float* kwbuf   = offs + L_SEQ * H_HEADS;     // L*HK
    float* vbuf    = kwbuf + L_SEQ * HK;         // L*C
    float* convbuf = vbuf + L_SEQ * C_DIM;       // L*C

    proj_small_kernel<<<L_SEQ, 64, 0, stream>>>(x, ww, wb, wg, ow, ob, og, wsizes, offs);
    proj_kernelw_kernel<<<L_SEQ, 256, 0, stream>>>(x, kw_w, kb, kg, kwbuf);
    gemm256_kernel<false, true><<<L_SEQ, 256, 0, stream>>>(x, vw, vb, vbuf);
    conv_kernel<<<L_SEQ, 256, 0, stream>>>(wsizes, offs, kwbuf, vbuf, convbuf);
    gemm256_kernel<true, false><<<L_SEQ, 256, 0, stream>>>(convbuf, outw, nullptr, y);
}

// Round 3
// 169.460 us; speedup vs baseline: 1.5122x; 1.5122x over previous
//
#include <hip/hip_runtime.h>
#include <math.h>

#define L_SEQ 4096
#define C_DIM 256
#define H_HEADS 8
#define K_MAX 64
#define D_HEAD 32
#define HALF_W 32
#define N_OFF 65          // 2*HALF_W + 1
#define HK 512            // H_HEADS * K_MAX
#define PW 768            // packed projection width: 512 (kernel) + 256 (v)

__device__ __forceinline__ float sigmoidf_(float x) { return 1.0f / (1.0f + expf(-x)); }

// ---------------- Pack kernel: concat [kernel_w | v_w] -> Wcat[256][768], biases -> biascat[768] ----------------
__global__ void pack_kernel(const float* __restrict__ kw_w, const float* __restrict__ vw,
                            const float* __restrict__ kb, const float* __restrict__ vb,
                            float* __restrict__ Wcat, float* __restrict__ biascat) {
    const int c = blockIdx.x;  // 0..255
    for (int j = threadIdx.x; j < PW; j += 256) {
        Wcat[c * PW + j] = (j < 512) ? kw_w[c * 512 + j] : vw[c * 256 + (j - 512)];
        if (c == 0) biascat[j] = (j < 512) ? kb[j] : vb[j - 512];
    }
}

// ---------------- small projections: verbatim round-0 kernel (bitwise-stable) ----------------
__global__ void proj_small_kernel(const float* __restrict__ x,
                                  const float* __restrict__ ww, const float* __restrict__ wb,
                                  const float* __restrict__ wg,
                                  const float* __restrict__ ow, const float* __restrict__ ob,
                                  const float* __restrict__ og,
                                  float* __restrict__ wsizes, float* __restrict__ offs) {
    const int l = blockIdx.x;
    const int lane = threadIdx.x;  // 0..63
    const float* xr = x + l * C_DIM;

    float accw[H_HEADS], acco[H_HEADS];
#pragma unroll
    for (int h = 0; h < H_HEADS; ++h) { accw[h] = 0.0f; acco[h] = 0.0f; }

#pragma unroll
    for (int i = 0; i < C_DIM / 64; ++i) {
        const int c = lane + i * 64;
        const float xv = xr[c];
        const float* wwc = ww + c * H_HEADS;
        const float* owc = ow + c * H_HEADS;
#pragma unroll
        for (int h = 0; h < H_HEADS; ++h) {
            accw[h] = fmaf(xv, wwc[h], accw[h]);
            acco[h] = fmaf(xv, owc[h], acco[h]);
        }
    }
#pragma unroll
    for (int off = 32; off > 0; off >>= 1) {
#pragma unroll
        for (int h = 0; h < H_HEADS; ++h) {
            accw[h] += __shfl_xor(accw[h], off);
            acco[h] += __shfl_xor(acco[h], off);
        }
    }
    if (lane == 0) {
        float zw[H_HEADS], zo[H_HEADS];
        float ssw = 0.0f, sso = 0.0f;
#pragma unroll
        for (int h = 0; h < H_HEADS; ++h) {
            zw[h] = accw[h] + wb[h];
            zo[h] = acco[h] + ob[h];
            ssw += zw[h] * zw[h];
            sso += zo[h] * zo[h];
        }
        const float rw = rsqrtf(ssw / (float)H_HEADS + 1e-6f);
        const float ro = rsqrtf(sso / (float)H_HEADS + 1e-6f);
#pragma unroll
        for (int h = 0; h < H_HEADS; ++h) {
            const float nw = wg[h] * zw[h] * rw;
            const float no = og[h] * zo[h] * ro;
            wsizes[l * H_HEADS + h] = 1.0f + sigmoidf_(nw) * 63.0f;
            offs[l * H_HEADS + h]   = tanhf(no) * 64.0f;
        }
    }
}

// ---------------- Tiled fp32 GEMM (sequential-k fmaf per output => bitwise == naive chain) ----------------
// BM=BN=64, BK=16, TM=TN=4, 256 threads.
template <bool ROUTE>
__global__ void gemm_tiled(const float* __restrict__ A, const float* __restrict__ B,
                           const float* __restrict__ biascat, int ldb,
                           float* __restrict__ out,
                           float* __restrict__ kwbuf, float* __restrict__ vbuf) {
    __shared__ float As[16][68];
    __shared__ float Bs[16][68];

    const int tid = threadIdx.x;
    const int tx = tid & 15;        // col group
    const int ty = tid >> 4;        // row group
    const int l0 = blockIdx.y * 64;
    const int n0 = blockIdx.x * 64;

    const int am = tid >> 2;          // 0..63
    const int ak = (tid & 3) * 4;     // 0,4,8,12
    const int bk = tid >> 4;          // 0..15
    const int bn = (tid & 15) * 4;    // 0..60

    float acc[4][4];
#pragma unroll
    for (int i = 0; i < 4; ++i)
#pragma unroll
        for (int j = 0; j < 4; ++j) acc[i][j] = 0.0f;

    for (int k0 = 0; k0 < C_DIM; k0 += 16) {
        const float4 av = *(const float4*)&A[(l0 + am) * C_DIM + k0 + ak];
        const float4 bv = *(const float4*)&B[(k0 + bk) * ldb + n0 + bn];
        __syncthreads();
        As[ak + 0][am] = av.x;
        As[ak + 1][am] = av.y;
        As[ak + 2][am] = av.z;
        As[ak + 3][am] = av.w;
        *(float4*)&Bs[bk][bn] = bv;
        __syncthreads();
#pragma unroll
        for (int kk = 0; kk < 16; ++kk) {
            const float4 a4 = *(const float4*)&As[kk][ty * 4];
            const float4 b4 = *(const float4*)&Bs[kk][tx * 4];
            const float ar[4] = {a4.x, a4.y, a4.z, a4.w};
            const float br[4] = {b4.x, b4.y, b4.z, b4.w};
#pragma unroll
            for (int i = 0; i < 4; ++i)
#pragma unroll
                for (int j = 0; j < 4; ++j)
                    acc[i][j] = fmaf(ar[i], br[j], acc[i][j]);
        }
    }

    const int g0 = n0 + tx * 4;
    if (ROUTE) {
        const float4 bz = *(const float4*)&biascat[g0];
        float* dst;
        int stride, col;
        if (g0 < 512) { dst = kwbuf; stride = 512; col = g0; }
        else          { dst = vbuf;  stride = 256; col = g0 - 512; }
#pragma unroll
        for (int i = 0; i < 4; ++i) {
            const int row = l0 + ty * 4 + i;
            float4 o;
            o.x = acc[i][0] + bz.x;
            o.y = acc[i][1] + bz.y;
            o.z = acc[i][2] + bz.z;
            o.w = acc[i][3] + bz.w;
            *(float4*)&dst[row * stride + col] = o;
        }
    } else {
#pragma unroll
        for (int i = 0; i < 4; ++i) {
            const int row = l0 + ty * 4 + i;
            float4 o;
            o.x = acc[i][0] * sigmoidf_(acc[i][0]);
            o.y = acc[i][1] * sigmoidf_(acc[i][1]);
            o.z = acc[i][2] * sigmoidf_(acc[i][2]);
            o.w = acc[i][3] * sigmoidf_(acc[i][3]);
            *(float4*)&out[row * C_DIM + g0] = o;
        }
    }
}

// ---------------- norm_kw: rmsnorm(512)+silu, verbatim round-0 reduction (LDS tree) ----------------
__global__ void norm_kw(float* __restrict__ kwbuf, const float* __restrict__ kg) {
    const int l = blockIdx.x;
    const int j = threadIdx.x;  // 0..255
    __shared__ float red[256];
    __shared__ float rs_s;
    float* row = kwbuf + l * HK;
    const float z0 = row[j];
    const float z1 = row[j + 256];

    red[j] = z0 * z0 + z1 * z1;
    __syncthreads();
    for (int s = 128; s > 0; s >>= 1) {
        if (j < s) red[j] += red[j + s];
        __syncthreads();
    }
    if (j == 0) rs_s = rsqrtf(red[0] / (float)HK + 1e-6f);
    __syncthreads();
    const float rs = rs_s;

    const float n0 = kg[j] * z0 * rs;
    const float n1 = kg[j + 256] * z1 * rs;
    row[j]       = n0 * sigmoidf_(n0);
    row[j + 256] = n1 * sigmoidf_(n1);
}

// ---------------- adaptive local conv: verbatim round-0 ----------------
__global__ void conv_kernel(const float* __restrict__ wsizes, const float* __restrict__ offs,
                            const float* __restrict__ kw, const float* __restrict__ v,
                            float* __restrict__ out) {
    const int l = blockIdx.x;
    const int tid = threadIdx.x;

    __shared__ float attn[H_HEADS][N_OFF];
    __shared__ int   pfl[H_HEADS][N_OFF];
    __shared__ float frac[H_HEADS][N_OFF];
    __shared__ float inv_denom[H_HEADS];

    for (int t = tid; t < H_HEADS * N_OFF; t += 256) {
        const int h = t / N_OFF;
        const int n = t - h * N_OFF;
        const float ws  = wsizes[l * H_HEADS + h];
        const float off = offs[l * H_HEADS + h];
        const float local = (float)(n - HALF_W);
        const float neighbor = (float)l + off + local;
        const bool valid = (neighbor >= 0.0f) && (neighbor < (float)L_SEQ);
        const float nc = fminf(fmaxf(neighbor, 0.0f), (float)(L_SEQ - 1));

        const float rel = fabsf(local) / (ws * 0.5f + 1e-6f);
        const float mask = sigmoidf_(5.0f * (1.0f - rel)) * (valid ? 1.0f : 0.0f);

        const float kidx = fminf(rel, 1.0f) * (float)(K_MAX - 1);
        int ifl = (int)kidx;
        ifl = min(ifl, K_MAX - 2);
        const float wce = kidx - (float)ifl;
        const float kf = kw[l * HK + h * K_MAX + ifl];
        const float kc = kw[l * HK + h * K_MAX + ifl + 1];
        attn[h][n] = (kf * (1.0f - wce) + kc * wce) * mask;

        int p = (int)floorf(nc);
        p = min(max(p, 0), L_SEQ - 1);
        pfl[h][n] = p;
        frac[h][n] = nc - (float)p;
    }
    __syncthreads();

    if (tid < H_HEADS) {
        float s = 0.0f;
        for (int n = 0; n < N_OFF; ++n) s += attn[tid][n];
        inv_denom[tid] = 1.0f / (s + 1e-6f);
    }
    __syncthreads();

    const int h = tid >> 5;   // 0..7
    const int d = tid & 31;   // 0..31
    float acc = 0.0f;
    for (int n = 0; n < N_OFF; ++n) {
        const float a = attn[h][n];
        const int   p = pfl[h][n];
        const float f = frac[h][n];
        const int  pc = min(p + 1, L_SEQ - 1);
        const float vf = v[p * C_DIM + h * D_HEAD + d];
        const float vc = v[pc * C_DIM + h * D_HEAD + d];
        acc = fmaf(a, vf + f * (vc - vf), acc);
    }
    out[l * C_DIM + h * D_HEAD + d] = acc * inv_denom[h];
}

extern "C" void kernel_launch(void* const* d_in, const int* in_sizes, int n_in,
                              void* d_out, int out_size, void* d_ws, size_t ws_size,
                              hipStream_t stream) {
    const float* x    = (const float*)d_in[0];
    const float* ww   = (const float*)d_in[1];
    const float* wb   = (const float*)d_in[2];
    const float* wg   = (const float*)d_in[3];
    const float* ow   = (const float*)d_in[4];
    const float* ob   = (const float*)d_in[5];
    const float* og   = (const float*)d_in[6];
    const float* kw_w = (const float*)d_in[7];
    const float* kb   = (const float*)d_in[8];
    const float* kg   = (const float*)d_in[9];
    const float* vw   = (const float*)d_in[10];
    const float* vb   = (const float*)d_in[11];
    const float* outw = (const float*)d_in[12];
    float* y = (float*)d_out;

    // Workspace layout (total 4,259,840 floats = round-0's proven footprint).
    // Wcat/biascat alias the convbuf region: Wcat's lifetime (pack -> proj GEMM)
    // ends before convbuf's begins (conv_kernel -> final GEMM).
    float* ws_f     = (float*)d_ws;
    float* convbuf  = ws_f;                           // 4096*256  (region0)
    float* Wcat     = ws_f;                           //   alias: 256*768
    float* biascat  = Wcat + 256 * PW;                //   alias: 768 (fits: 197,376 < 1,048,576)
    float* kwbuf    = convbuf + L_SEQ * C_DIM;        // 4096*512
    float* vbuf     = kwbuf + L_SEQ * HK;             // 4096*256
    float* wsizes   = vbuf + L_SEQ * C_DIM;           // 4096*8
    float* offs     = wsizes + L_SEQ * H_HEADS;       // 4096*8

    pack_kernel<<<256, 256, 0, stream>>>(kw_w, vw, kb, vb, Wcat, biascat);
    proj_small_kernel<<<L_SEQ, 64, 0, stream>>>(x, ww, wb, wg, ow, ob, og, wsizes, offs);
    gemm_tiled<true><<<dim3(PW / 64, L_SEQ / 64), 256, 0, stream>>>(
        x, Wcat, biascat, PW, nullptr, kwbuf, vbuf);
    norm_kw<<<L_SEQ, 256, 0, stream>>>(kwbuf, kg);
    conv_kernel<<<L_SEQ, 256, 0, stream>>>(wsizes, offs, kwbuf, vbuf, convbuf);
    gemm_tiled<false><<<dim3(C_DIM / 64, L_SEQ / 64), 256, 0, stream>>>(
        convbuf, outw, nullptr, C_DIM, y, nullptr, nullptr);
}

// Round 5
// 163.776 us; speedup vs baseline: 1.5647x; 1.0347x over previous
//
#include <hip/hip_runtime.h>
#include <math.h>

#define L_SEQ 4096
#define C_DIM 256
#define H_HEADS 8
#define K_MAX 64
#define D_HEAD 32
#define HALF_W 32
#define N_OFF 65          // 2*HALF_W + 1
#define HK 512            // H_HEADS * K_MAX

__device__ __forceinline__ float sigmoidf_(float x) { return 1.0f / (1.0f + expf(-x)); }

// ================= K1: fused projection GEMM =================
// [4096 x 768] = x[4096x256] @ [kernel_w | v_w], bias epilogue, routed stores.
// BM=BN=64, BK=16, TM=TN=4, 256 threads, grid (12, 64).
// Register-prefetch pipeline; per-output sequential-k fmaf (bitwise == round 3).
__global__ void proj_gemm(const float* __restrict__ A, const float* __restrict__ kw_w,
                          const float* __restrict__ vw, const float* __restrict__ kb,
                          const float* __restrict__ vb,
                          float* __restrict__ kwbuf, float* __restrict__ vbuf) {
    __shared__ float As[16][68];
    __shared__ float Bs[16][68];

    const int tid = threadIdx.x;
    const int tx = tid & 15;
    const int ty = tid >> 4;
    const int l0 = blockIdx.y * 64;
    const int n0 = blockIdx.x * 64;

    const int am = tid >> 2;          // 0..63
    const int ak = (tid & 3) * 4;     // 0,4,8,12
    const int bk = tid >> 4;          // 0..15
    const int bn = (tid & 15) * 4;    // 0..60

    // region select (block-uniform: n0 is a multiple of 64, regions split at 512)
    const float* Bsrc;
    int ldb, coff;
    if (n0 < 512) { Bsrc = kw_w; ldb = 512; coff = n0; }
    else          { Bsrc = vw;   ldb = 256; coff = n0 - 512; }

    float acc[4][4];
#pragma unroll
    for (int i = 0; i < 4; ++i)
#pragma unroll
        for (int jj = 0; jj < 4; ++jj) acc[i][jj] = 0.0f;

    float4 av = *(const float4*)&A[(l0 + am) * C_DIM + ak];
    float4 bv = *(const float4*)&Bsrc[bk * ldb + coff + bn];

    for (int k0 = 0; k0 < C_DIM; k0 += 16) {
        __syncthreads();
        As[ak + 0][am] = av.x;
        As[ak + 1][am] = av.y;
        As[ak + 2][am] = av.z;
        As[ak + 3][am] = av.w;
        *(float4*)&Bs[bk][bn] = bv;
        __syncthreads();
        if (k0 + 16 < C_DIM) {
            av = *(const float4*)&A[(l0 + am) * C_DIM + (k0 + 16) + ak];
            bv = *(const float4*)&Bsrc[(k0 + 16 + bk) * ldb + coff + bn];
        }
#pragma unroll
        for (int kk = 0; kk < 16; ++kk) {
            const float4 a4 = *(const float4*)&As[kk][ty * 4];
            const float4 b4 = *(const float4*)&Bs[kk][tx * 4];
            const float ar[4] = {a4.x, a4.y, a4.z, a4.w};
            const float br[4] = {b4.x, b4.y, b4.z, b4.w};
#pragma unroll
            for (int i = 0; i < 4; ++i)
#pragma unroll
                for (int jj = 0; jj < 4; ++jj)
                    acc[i][jj] = fmaf(ar[i], br[jj], acc[i][jj]);
        }
    }

    const int g0 = n0 + tx * 4;
    float4 bz;
    float* dst;
    int stride, col;
    if (g0 < 512) { bz = *(const float4*)&kb[g0];       dst = kwbuf; stride = 512; col = g0; }
    else          { bz = *(const float4*)&vb[g0 - 512]; dst = vbuf;  stride = 256; col = g0 - 512; }
#pragma unroll
    for (int i = 0; i < 4; ++i) {
        const int row = l0 + ty * 4 + i;
        float4 o;
        o.x = acc[i][0] + bz.x;
        o.y = acc[i][1] + bz.y;
        o.z = acc[i][2] + bz.z;
        o.w = acc[i][3] + bz.w;
        *(float4*)&dst[row * stride + col] = o;
    }
}

// ================= K2: fused norm + small-proj + adaptive local conv =================
// One 256-thread block per row l.
// Phase A: rmsnorm(512)+silu of kwraw row l (bitwise == round-3 norm_kw).
// Phase B: window/offset projections for row l on wave 0 (bitwise == round-3 proj_small).
// Stages 1-3: bitwise == round-3 conv_kernel, reading LDS instead of global.
__global__ void conv_fused(const float* __restrict__ x,
                           const float* __restrict__ ww, const float* __restrict__ wb,
                           const float* __restrict__ wg,
                           const float* __restrict__ ow, const float* __restrict__ ob,
                           const float* __restrict__ og,
                           const float* __restrict__ kg,
                           const float* __restrict__ kwraw, const float* __restrict__ v,
                           float* __restrict__ out) {
    const int l = blockIdx.x;
    const int tid = threadIdx.x;

    __shared__ float red[256];
    __shared__ float rs_s;
    __shared__ float kwrow[HK];
    __shared__ float wsz[H_HEADS], ofs[H_HEADS];
    __shared__ float attn[H_HEADS][N_OFF];
    __shared__ int   pfl[H_HEADS][N_OFF];
    __shared__ float frac[H_HEADS][N_OFF];
    __shared__ float inv_denom[H_HEADS];

    // ---- Phase A: rmsnorm(512) + silu ----
    {
        const int j = tid;
        const float* row = kwraw + l * HK;
        const float z0 = row[j];
        const float z1 = row[j + 256];
        red[j] = z0 * z0 + z1 * z1;
        __syncthreads();
        for (int s = 128; s > 0; s >>= 1) {
            if (j < s) red[j] += red[j + s];
            __syncthreads();
        }
        if (j == 0) rs_s = rsqrtf(red[0] / (float)HK + 1e-6f);
        __syncthreads();
        const float rs = rs_s;
        const float n0v = kg[j] * z0 * rs;
        const float n1v = kg[j + 256] * z1 * rs;
        kwrow[j]       = n0v * sigmoidf_(n0v);
        kwrow[j + 256] = n1v * sigmoidf_(n1v);
    }

    // ---- Phase B: small projections (wave 0) ----
    if (tid < 64) {
        const int lane = tid;
        const float* xr = x + l * C_DIM;
        float accw[H_HEADS], acco[H_HEADS];
#pragma unroll
        for (int h = 0; h < H_HEADS; ++h) { accw[h] = 0.0f; acco[h] = 0.0f; }
#pragma unroll
        for (int i = 0; i < C_DIM / 64; ++i) {
            const int c = lane + i * 64;
            const float xv = xr[c];
            const float* wwc = ww + c * H_HEADS;
            const float* owc = ow + c * H_HEADS;
#pragma unroll
            for (int h = 0; h < H_HEADS; ++h) {
                accw[h] = fmaf(xv, wwc[h], accw[h]);
                acco[h] = fmaf(xv, owc[h], acco[h]);
            }
        }
#pragma unroll
        for (int off = 32; off > 0; off >>= 1) {
#pragma unroll
            for (int h = 0; h < H_HEADS; ++h) {
                accw[h] += __shfl_xor(accw[h], off);
                acco[h] += __shfl_xor(acco[h], off);
            }
        }
        if (lane == 0) {
            float zw[H_HEADS], zo[H_HEADS];
            float ssw = 0.0f, sso = 0.0f;
#pragma unroll
            for (int h = 0; h < H_HEADS; ++h) {
                zw[h] = accw[h] + wb[h];
                zo[h] = acco[h] + ob[h];
                ssw += zw[h] * zw[h];
                sso += zo[h] * zo[h];
            }
            const float rw = rsqrtf(ssw / (float)H_HEADS + 1e-6f);
            const float ro = rsqrtf(sso / (float)H_HEADS + 1e-6f);
#pragma unroll
            for (int h = 0; h < H_HEADS; ++h) {
                const float nw = wg[h] * zw[h] * rw;
                const float no = og[h] * zo[h] * ro;
                wsz[h] = 1.0f + sigmoidf_(nw) * 63.0f;
                ofs[h] = tanhf(no) * 64.0f;
            }
        }
    }
    __syncthreads();

    // ---- Stage 1: attention taps ----
    for (int t = tid; t < H_HEADS * N_OFF; t += 256) {
        const int h = t / N_OFF;
        const int n = t - h * N_OFF;
        const float ws  = wsz[h];
        const float off = ofs[h];
        const float local = (float)(n - HALF_W);
        const float neighbor = (float)l + off + local;
        const bool valid = (neighbor >= 0.0f) && (neighbor < (float)L_SEQ);
        const float nc = fminf(fmaxf(neighbor, 0.0f), (float)(L_SEQ - 1));

        const float rel = fabsf(local) / (ws * 0.5f + 1e-6f);
        const float mask = sigmoidf_(5.0f * (1.0f - rel)) * (valid ? 1.0f : 0.0f);

        const float kidx = fminf(rel, 1.0f) * (float)(K_MAX - 1);
        int ifl = (int)kidx;
        ifl = min(ifl, K_MAX - 2);
        const float wce = kidx - (float)ifl;
        const float kf = kwrow[h * K_MAX + ifl];
        const float kc = kwrow[h * K_MAX + ifl + 1];
        attn[h][n] = (kf * (1.0f - wce) + kc * wce) * mask;

        int p = (int)floorf(nc);
        p = min(max(p, 0), L_SEQ - 1);
        pfl[h][n] = p;
        frac[h][n] = nc - (float)p;
    }
    __syncthreads();

    // ---- Stage 2: per-head denominators (sequential order preserved) ----
    if (tid < H_HEADS) {
        float s = 0.0f;
        for (int n = 0; n < N_OFF; ++n) s += attn[tid][n];
        inv_denom[tid] = 1.0f / (s + 1e-6f);
    }
    __syncthreads();

    // ---- Stage 3: gather & accumulate ----
    const int h = tid >> 5;
    const int d = tid & 31;
    float acc = 0.0f;
    for (int n = 0; n < N_OFF; ++n) {
        const float a = attn[h][n];
        const int   p = pfl[h][n];
        const float f = frac[h][n];
        const int  pc = min(p + 1, L_SEQ - 1);
        const float vf = v[p * C_DIM + h * D_HEAD + d];
        const float vc = v[pc * C_DIM + h * D_HEAD + d];
        acc = fmaf(a, vf + f * (vc - vf), acc);
    }
    out[l * C_DIM + h * D_HEAD + d] = acc * inv_denom[h];
}

// ================= K3: out projection GEMM + silu =================
// BM=32, BN=64, BK=16, TM=2, TN=4, 256 threads, grid (4, 128) = 512 blocks.
__global__ void out_gemm(const float* __restrict__ A, const float* __restrict__ W,
                         float* __restrict__ out) {
    __shared__ float As[16][36];
    __shared__ float Bs[16][68];

    const int tid = threadIdx.x;
    const int tx = tid & 15;
    const int ty = tid >> 4;          // 0..15, 2 rows each
    const int l0 = blockIdx.y * 32;
    const int n0 = blockIdx.x * 64;

    const int bk = tid >> 4;
    const int bn = (tid & 15) * 4;
    const int am = (tid & 127) >> 2;  // 0..31
    const int ak = (tid & 3) * 4;
    const bool aload = tid < 128;

    float acc[2][4];
#pragma unroll
    for (int i = 0; i < 2; ++i)
#pragma unroll
        for (int jj = 0; jj < 4; ++jj) acc[i][jj] = 0.0f;

    float4 av, bv;
    if (aload) av = *(const float4*)&A[(l0 + am) * C_DIM + ak];
    bv = *(const float4*)&W[bk * C_DIM + n0 + bn];

    for (int k0 = 0; k0 < C_DIM; k0 += 16) {
        __syncthreads();
        if (aload) {
            As[ak + 0][am] = av.x;
            As[ak + 1][am] = av.y;
            As[ak + 2][am] = av.z;
            As[ak + 3][am] = av.w;
        }
        *(float4*)&Bs[bk][bn] = bv;
        __syncthreads();
        if (k0 + 16 < C_DIM) {
            if (aload) av = *(const float4*)&A[(l0 + am) * C_DIM + (k0 + 16) + ak];
            bv = *(const float4*)&W[(k0 + 16 + bk) * C_DIM + n0 + bn];
        }
#pragma unroll
        for (int kk = 0; kk < 16; ++kk) {
            const float a0 = As[kk][ty * 2 + 0];
            const float a1 = As[kk][ty * 2 + 1];
            const float4 b4 = *(const float4*)&Bs[kk][tx * 4];
            const float br[4] = {b4.x, b4.y, b4.z, b4.w};
#pragma unroll
            for (int jj = 0; jj < 4; ++jj) {
                acc[0][jj] = fmaf(a0, br[jj], acc[0][jj]);
                acc[1][jj] = fmaf(a1, br[jj], acc[1][jj]);
            }
        }
    }

    const int g0 = n0 + tx * 4;
#pragma unroll
    for (int i = 0; i < 2; ++i) {
        const int row = l0 + ty * 2 + i;
        float4 o;
        o.x = acc[i][0] * sigmoidf_(acc[i][0]);
        o.y = acc[i][1] * sigmoidf_(acc[i][1]);
        o.z = acc[i][2] * sigmoidf_(acc[i][2]);
        o.w = acc[i][3] * sigmoidf_(acc[i][3]);
        *(float4*)&out[row * C_DIM + g0] = o;
    }
}

extern "C" void kernel_launch(void* const* d_in, const int* in_sizes, int n_in,
                              void* d_out, int out_size, void* d_ws, size_t ws_size,
                              hipStream_t stream) {
    const float* x    = (const float*)d_in[0];
    const float* ww   = (const float*)d_in[1];
    const float* wb   = (const float*)d_in[2];
    const float* wg   = (const float*)d_in[3];
    const float* ow   = (const float*)d_in[4];
    const float* ob   = (const float*)d_in[5];
    const float* og   = (const float*)d_in[6];
    const float* kw_w = (const float*)d_in[7];
    const float* kb   = (const float*)d_in[8];
    const float* kg   = (const float*)d_in[9];
    const float* vw   = (const float*)d_in[10];
    const float* vb   = (const float*)d_in[11];
    const float* outw = (const float*)d_in[12];
    float* y = (float*)d_out;

    float* ws_f    = (float*)d_ws;
    float* kwbuf   = ws_f;                       // 4096*512 (raw z+bias)
    float* vbuf    = kwbuf + L_SEQ * HK;         // 4096*256
    float* convbuf = vbuf + L_SEQ * C_DIM;       // 4096*256

    proj_gemm<<<dim3(12, L_SEQ / 64), 256, 0, stream>>>(x, kw_w, vw, kb, vb, kwbuf, vbuf);
    conv_fused<<<L_SEQ, 256, 0, stream>>>(x, ww, wb, wg, ow, ob, og, kg, kwbuf, vbuf, convbuf);
    out_gemm<<<dim3(C_DIM / 64, L_SEQ / 32), 256, 0, stream>>>(convbuf, outw, y);
}

// Round 6
// 154.213 us; speedup vs baseline: 1.6617x; 1.0620x over previous
//
#include <hip/hip_runtime.h>
#include <math.h>

#define L_SEQ 4096
#define C_DIM 256
#define H_HEADS 8
#define K_MAX 64
#define D_HEAD 32
#define HALF_W 32
#define N_OFF 65          // 2*HALF_W + 1
#define HK 512            // H_HEADS * K_MAX

__device__ __forceinline__ float sigmoidf_(float x) { return 1.0f / (1.0f + expf(-x)); }

// ================= K1: fused projection GEMM =================
// [4096 x 768] = x[4096x256] @ [kernel_w | v_w], bias epilogue, routed stores.
// BM=128, BN=64, BK=16, TM=8, TN=4, 256 threads, grid (12, 32).
// Per-output sequential-k fmaf chain (k=0..255) => bitwise == previous rounds.
__global__ void proj_gemm(const float* __restrict__ A, const float* __restrict__ kw_w,
                          const float* __restrict__ vw, const float* __restrict__ kb,
                          const float* __restrict__ vb,
                          float* __restrict__ kwbuf, float* __restrict__ vbuf) {
    __shared__ float As[16][132];   // [k][m], pad 132 (mult of 4 -> b128-aligned reads)
    __shared__ float Bs[16][68];    // [k][n]

    const int tid = threadIdx.x;
    const int tx = tid & 15;          // col group (4 cols)
    const int ty = tid >> 4;          // row group (8 rows)
    const int l0 = blockIdx.y * 128;
    const int n0 = blockIdx.x * 64;

    // A loads: 512 float4 needed; thread loads q=tid and q=tid+256.
    const int ar0 = tid >> 2;               // 0..63
    const int ac0 = (tid & 3) * 4;          // 0,4,8,12
    const int ar1 = ar0 + 64;               // 64..127
    // B loads: 1 float4 per thread
    const int bk = tid >> 4;                // 0..15
    const int bn = (tid & 15) * 4;          // 0..60

    // region select (block-uniform: regions split at 512, n0 multiple of 64)
    const float* Bsrc;
    int ldb, coff;
    if (n0 < 512) { Bsrc = kw_w; ldb = 512; coff = n0; }
    else          { Bsrc = vw;   ldb = 256; coff = n0 - 512; }

    float acc[8][4];
#pragma unroll
    for (int i = 0; i < 8; ++i)
#pragma unroll
        for (int jj = 0; jj < 4; ++jj) acc[i][jj] = 0.0f;

    float4 av0 = *(const float4*)&A[(l0 + ar0) * C_DIM + ac0];
    float4 av1 = *(const float4*)&A[(l0 + ar1) * C_DIM + ac0];
    float4 bv  = *(const float4*)&Bsrc[bk * ldb + coff + bn];

    for (int k0 = 0; k0 < C_DIM; k0 += 16) {
        __syncthreads();
        As[ac0 + 0][ar0] = av0.x;
        As[ac0 + 1][ar0] = av0.y;
        As[ac0 + 2][ar0] = av0.z;
        As[ac0 + 3][ar0] = av0.w;
        As[ac0 + 0][ar1] = av1.x;
        As[ac0 + 1][ar1] = av1.y;
        As[ac0 + 2][ar1] = av1.z;
        As[ac0 + 3][ar1] = av1.w;
        *(float4*)&Bs[bk][bn] = bv;
        __syncthreads();
        if (k0 + 16 < C_DIM) {
            av0 = *(const float4*)&A[(l0 + ar0) * C_DIM + (k0 + 16) + ac0];
            av1 = *(const float4*)&A[(l0 + ar1) * C_DIM + (k0 + 16) + ac0];
            bv  = *(const float4*)&Bsrc[(k0 + 16 + bk) * ldb + coff + bn];
        }
#pragma unroll
        for (int kk = 0; kk < 16; ++kk) {
            const float4 a4lo = *(const float4*)&As[kk][ty * 8];
            const float4 a4hi = *(const float4*)&As[kk][ty * 8 + 4];
            const float4 b4   = *(const float4*)&Bs[kk][tx * 4];
            const float ar[8] = {a4lo.x, a4lo.y, a4lo.z, a4lo.w,
                                 a4hi.x, a4hi.y, a4hi.z, a4hi.w};
            const float br[4] = {b4.x, b4.y, b4.z, b4.w};
#pragma unroll
            for (int i = 0; i < 8; ++i)
#pragma unroll
                for (int jj = 0; jj < 4; ++jj)
                    acc[i][jj] = fmaf(ar[i], br[jj], acc[i][jj]);
        }
    }

    const int g0 = n0 + tx * 4;
    float4 bz;
    float* dst;
    int stride, col;
    if (g0 < 512) { bz = *(const float4*)&kb[g0];       dst = kwbuf; stride = 512; col = g0; }
    else          { bz = *(const float4*)&vb[g0 - 512]; dst = vbuf;  stride = 256; col = g0 - 512; }
#pragma unroll
    for (int i = 0; i < 8; ++i) {
        const int row = l0 + ty * 8 + i;
        float4 o;
        o.x = acc[i][0] + bz.x;
        o.y = acc[i][1] + bz.y;
        o.z = acc[i][2] + bz.z;
        o.w = acc[i][3] + bz.w;
        *(float4*)&dst[row * stride + col] = o;
    }
}

// ================= K2: fused norm + small-proj + adaptive local conv =================
// One 256-thread block per row l. All expressions/reduction orders feeding the
// attn denominator are bitwise == round 5. Stage-1 results packed into one
// float4 {attn, frac, word_off_floor, word_off_ceil} per (h,n) for stage 3.
__global__ void conv_fused(const float* __restrict__ x,
                           const float* __restrict__ ww, const float* __restrict__ wb,
                           const float* __restrict__ wg,
                           const float* __restrict__ ow, const float* __restrict__ ob,
                           const float* __restrict__ og,
                           const float* __restrict__ kg,
                           const float* __restrict__ kwraw, const float* __restrict__ v,
                           float* __restrict__ out) {
    const int l = blockIdx.x;
    const int tid = threadIdx.x;

    __shared__ float red[256];
    __shared__ float rs_s;
    __shared__ float kwrow[HK];
    __shared__ float wsz[H_HEADS], ofs[H_HEADS];
    __shared__ float4 tap[H_HEADS][N_OFF];   // {attn, frac, as_float(offF), as_float(offC)}
    __shared__ float inv_denom[H_HEADS];

    // ---- Phase A: rmsnorm(512) + silu (bitwise == round 5) ----
    {
        const int j = tid;
        const float* row = kwraw + l * HK;
        const float z0 = row[j];
        const float z1 = row[j + 256];
        red[j] = z0 * z0 + z1 * z1;
        __syncthreads();
        for (int s = 128; s > 0; s >>= 1) {
            if (j < s) red[j] += red[j + s];
            __syncthreads();
        }
        if (j == 0) rs_s = rsqrtf(red[0] / (float)HK + 1e-6f);
        __syncthreads();
        const float rs = rs_s;
        const float n0v = kg[j] * z0 * rs;
        const float n1v = kg[j + 256] * z1 * rs;
        kwrow[j]       = n0v * sigmoidf_(n0v);
        kwrow[j + 256] = n1v * sigmoidf_(n1v);
    }

    // ---- Phase B: small projections (wave 0); tail parallel over 8 lanes ----
    if (tid < 64) {
        const int lane = tid;
        const float* xr = x + l * C_DIM;
        float accw[H_HEADS], acco[H_HEADS];
#pragma unroll
        for (int h = 0; h < H_HEADS; ++h) { accw[h] = 0.0f; acco[h] = 0.0f; }
#pragma unroll
        for (int i = 0; i < C_DIM / 64; ++i) {
            const int c = lane + i * 64;
            const float xv = xr[c];
            const float* wwc = ww + c * H_HEADS;
            const float* owc = ow + c * H_HEADS;
#pragma unroll
            for (int h = 0; h < H_HEADS; ++h) {
                accw[h] = fmaf(xv, wwc[h], accw[h]);
                acco[h] = fmaf(xv, owc[h], acco[h]);
            }
        }
#pragma unroll
        for (int off = 32; off > 0; off >>= 1) {
#pragma unroll
            for (int h = 0; h < H_HEADS; ++h) {
                accw[h] += __shfl_xor(accw[h], off);
                acco[h] += __shfl_xor(acco[h], off);
            }
        }
        // After a full butterfly every lane holds bitwise-identical sums
        // (per-stage pair additions are commutative-rounding-identical), so
        // lanes 0..7 compute ssw/sso redundantly in the SAME h order (same
        // bits as round-5's lane-0 computation) and each finishes one head.
        if (lane < H_HEADS) {
            float zw[H_HEADS], zo[H_HEADS];
            float ssw = 0.0f, sso = 0.0f;
#pragma unroll
            for (int h = 0; h < H_HEADS; ++h) {
                zw[h] = accw[h] + wb[h];
                zo[h] = acco[h] + ob[h];
                ssw += zw[h] * zw[h];
                sso += zo[h] * zo[h];
            }
            const float rw = rsqrtf(ssw / (float)H_HEADS + 1e-6f);
            const float ro = rsqrtf(sso / (float)H_HEADS + 1e-6f);
            const float nw = wg[lane] * zw[lane] * rw;
            const float no = og[lane] * zo[lane] * ro;
            wsz[lane] = 1.0f + sigmoidf_(nw) * 63.0f;
            ofs[lane] = tanhf(no) * 64.0f;
        }
    }
    __syncthreads();

    // ---- Stage 1: attention taps (expressions bitwise == round 5) ----
    for (int t = tid; t < H_HEADS * N_OFF; t += 256) {
        const int h = t / N_OFF;
        const int n = t - h * N_OFF;
        const float ws  = wsz[h];
        const float off = ofs[h];
        const float local = (float)(n - HALF_W);
        const float neighbor = (float)l + off + local;
        const bool valid = (neighbor >= 0.0f) && (neighbor < (float)L_SEQ);
        const float nc = fminf(fmaxf(neighbor, 0.0f), (float)(L_SEQ - 1));

        const float rel = fabsf(local) / (ws * 0.5f + 1e-6f);
        const float mask = sigmoidf_(5.0f * (1.0f - rel)) * (valid ? 1.0f : 0.0f);

        const float kidx = fminf(rel, 1.0f) * (float)(K_MAX - 1);
        int ifl = (int)kidx;
        ifl = min(ifl, K_MAX - 2);
        const float wce = kidx - (float)ifl;
        const float kf = kwrow[h * K_MAX + ifl];
        const float kc = kwrow[h * K_MAX + ifl + 1];
        const float attnv = (kf * (1.0f - wce) + kc * wce) * mask;

        int p = (int)floorf(nc);
        p = min(max(p, 0), L_SEQ - 1);
        const int pc = min(p + 1, L_SEQ - 1);          // hoisted from stage 3, same expr
        const float fr = nc - (float)p;

        float4 tv;
        tv.x = attnv;
        tv.y = fr;
        tv.z = __int_as_float(p * C_DIM + h * D_HEAD);   // word offset (floor)
        tv.w = __int_as_float(pc * C_DIM + h * D_HEAD);  // word offset (ceil)
        tap[h][n] = tv;
    }
    __syncthreads();

    // ---- Stage 2: per-head denominators (serial n order preserved == round 5) ----
    if (tid < H_HEADS) {
        float s = 0.0f;
        for (int n = 0; n < N_OFF; ++n) s += tap[tid][n].x;
        inv_denom[tid] = 1.0f / (s + 1e-6f);
    }
    __syncthreads();

    // ---- Stage 3: gather & accumulate (same fmaf chain order; addresses precomputed) ----
    const int h = tid >> 5;
    const int d = tid & 31;
    float acc = 0.0f;
#pragma unroll 5
    for (int n = 0; n < N_OFF; ++n) {
        const float4 t = tap[h][n];
        const int bf = __float_as_int(t.z);
        const int bc = __float_as_int(t.w);
        const float vf = v[bf + d];
        const float vc = v[bc + d];
        acc = fmaf(t.x, fmaf(t.y, vc - vf, vf), acc);  // == fmaf(a, vf + f*(vc-vf), acc)
    }
    out[l * C_DIM + h * D_HEAD + d] = acc * inv_denom[h];
}

// ================= K3: out projection GEMM + silu (unchanged from round 5) =================
// BM=32, BN=64, BK=16, TM=2, TN=4, 256 threads, grid (4, 128) = 512 blocks.
__global__ void out_gemm(const float* __restrict__ A, const float* __restrict__ W,
                         float* __restrict__ out) {
    __shared__ float As[16][36];
    __shared__ float Bs[16][68];

    const int tid = threadIdx.x;
    const int tx = tid & 15;
    const int ty = tid >> 4;          // 0..15, 2 rows each
    const int l0 = blockIdx.y * 32;
    const int n0 = blockIdx.x * 64;

    const int bk = tid >> 4;
    const int bn = (tid & 15) * 4;
    const int am = (tid & 127) >> 2;  // 0..31
    const int ak = (tid & 3) * 4;
    const bool aload = tid < 128;

    float acc[2][4];
#pragma unroll
    for (int i = 0; i < 2; ++i)
#pragma unroll
        for (int jj = 0; jj < 4; ++jj) acc[i][jj] = 0.0f;

    float4 av, bv;
    if (aload) av = *(const float4*)&A[(l0 + am) * C_DIM + ak];
    bv = *(const float4*)&W[bk * C_DIM + n0 + bn];

    for (int k0 = 0; k0 < C_DIM; k0 += 16) {
        __syncthreads();
        if (aload) {
            As[ak + 0][am] = av.x;
            As[ak + 1][am] = av.y;
            As[ak + 2][am] = av.z;
            As[ak + 3][am] = av.w;
        }
        *(float4*)&Bs[bk][bn] = bv;
        __syncthreads();
        if (k0 + 16 < C_DIM) {
            if (aload) av = *(const float4*)&A[(l0 + am) * C_DIM + (k0 + 16) + ak];
            bv = *(const float4*)&W[(k0 + 16 + bk) * C_DIM + n0 + bn];
        }
#pragma unroll
        for (int kk = 0; kk < 16; ++kk) {
            const float a0 = As[kk][ty * 2 + 0];
            const float a1 = As[kk][ty * 2 + 1];
            const float4 b4 = *(const float4*)&Bs[kk][tx * 4];
            const float br[4] = {b4.x, b4.y, b4.z, b4.w};
#pragma unroll
            for (int jj = 0; jj < 4; ++jj) {
                acc[0][jj] = fmaf(a0, br[jj], acc[0][jj]);
                acc[1][jj] = fmaf(a1, br[jj], acc[1][jj]);
            }
        }
    }

    const int g0 = n0 + tx * 4;
#pragma unroll
    for (int i = 0; i < 2; ++i) {
        const int row = l0 + ty * 2 + i;
        float4 o;
        o.x = acc[i][0] * sigmoidf_(acc[i][0]);
        o.y = acc[i][1] * sigmoidf_(acc[i][1]);
        o.z = acc[i][2] * sigmoidf_(acc[i][2]);
        o.w = acc[i][3] * sigmoidf_(acc[i][3]);
        *(float4*)&out[row * C_DIM + g0] = o;
    }
}

extern "C" void kernel_launch(void* const* d_in, const int* in_sizes, int n_in,
                              void* d_out, int out_size, void* d_ws, size_t ws_size,
                              hipStream_t stream) {
    const float* x    = (const float*)d_in[0];
    const float* ww   = (const float*)d_in[1];
    const float* wb   = (const float*)d_in[2];
    const float* wg   = (const float*)d_in[3];
    const float* ow   = (const float*)d_in[4];
    const float* ob   = (const float*)d_in[5];
    const float* og   = (const float*)d_in[6];
    const float* kw_w = (const float*)d_in[7];
    const float* kb   = (const float*)d_in[8];
    const float* kg   = (const float*)d_in[9];
    const float* vw   = (const float*)d_in[10];
    const float* vb   = (const float*)d_in[11];
    const float* outw = (const float*)d_in[12];
    float* y = (float*)d_out;

    float* ws_f    = (float*)d_ws;
    float* kwbuf   = ws_f;                       // 4096*512 (raw z+bias)
    float* vbuf    = kwbuf + L_SEQ * HK;         // 4096*256
    float* convbuf = vbuf + L_SEQ * C_DIM;       // 4096*256

    proj_gemm<<<dim3(12, L_SEQ / 128), 256, 0, stream>>>(x, kw_w, vw, kb, vb, kwbuf, vbuf);
    conv_fused<<<L_SEQ, 256, 0, stream>>>(x, ww, wb, wg, ow, ob, og, kg, kwbuf, vbuf, convbuf);
    out_gemm<<<dim3(C_DIM / 64, L_SEQ / 32), 256, 0, stream>>>(convbuf, outw, y);
}

// Round 7
// 148.004 us; speedup vs baseline: 1.7314x; 1.0420x over previous
//
#include <hip/hip_runtime.h>
#include <math.h>

#define L_SEQ 4096
#define C_DIM 256
#define H_HEADS 8
#define K_MAX 64
#define D_HEAD 32
#define HALF_W 32
#define N_OFF 65          // 2*HALF_W + 1
#define HK 512            // H_HEADS * K_MAX

__device__ __forceinline__ float sigmoidf_(float x) { return 1.0f / (1.0f + expf(-x)); }

// ================= K1: fused projection GEMM (unchanged from round 6) =================
// BM=128, BN=64, BK=16, TM=8, TN=4, 256 threads, grid (12, 32).
__global__ void proj_gemm(const float* __restrict__ A, const float* __restrict__ kw_w,
                          const float* __restrict__ vw, const float* __restrict__ kb,
                          const float* __restrict__ vb,
                          float* __restrict__ kwbuf, float* __restrict__ vbuf) {
    __shared__ float As[16][132];
    __shared__ float Bs[16][68];

    const int tid = threadIdx.x;
    const int tx = tid & 15;
    const int ty = tid >> 4;
    const int l0 = blockIdx.y * 128;
    const int n0 = blockIdx.x * 64;

    const int ar0 = tid >> 2;
    const int ac0 = (tid & 3) * 4;
    const int ar1 = ar0 + 64;
    const int bk = tid >> 4;
    const int bn = (tid & 15) * 4;

    const float* Bsrc;
    int ldb, coff;
    if (n0 < 512) { Bsrc = kw_w; ldb = 512; coff = n0; }
    else          { Bsrc = vw;   ldb = 256; coff = n0 - 512; }

    float acc[8][4];
#pragma unroll
    for (int i = 0; i < 8; ++i)
#pragma unroll
        for (int jj = 0; jj < 4; ++jj) acc[i][jj] = 0.0f;

    float4 av0 = *(const float4*)&A[(l0 + ar0) * C_DIM + ac0];
    float4 av1 = *(const float4*)&A[(l0 + ar1) * C_DIM + ac0];
    float4 bv  = *(const float4*)&Bsrc[bk * ldb + coff + bn];

    for (int k0 = 0; k0 < C_DIM; k0 += 16) {
        __syncthreads();
        As[ac0 + 0][ar0] = av0.x;
        As[ac0 + 1][ar0] = av0.y;
        As[ac0 + 2][ar0] = av0.z;
        As[ac0 + 3][ar0] = av0.w;
        As[ac0 + 0][ar1] = av1.x;
        As[ac0 + 1][ar1] = av1.y;
        As[ac0 + 2][ar1] = av1.z;
        As[ac0 + 3][ar1] = av1.w;
        *(float4*)&Bs[bk][bn] = bv;
        __syncthreads();
        if (k0 + 16 < C_DIM) {
            av0 = *(const float4*)&A[(l0 + ar0) * C_DIM + (k0 + 16) + ac0];
            av1 = *(const float4*)&A[(l0 + ar1) * C_DIM + (k0 + 16) + ac0];
            bv  = *(const float4*)&Bsrc[(k0 + 16 + bk) * ldb + coff + bn];
        }
#pragma unroll
        for (int kk = 0; kk < 16; ++kk) {
            const float4 a4lo = *(const float4*)&As[kk][ty * 8];
            const float4 a4hi = *(const float4*)&As[kk][ty * 8 + 4];
            const float4 b4   = *(const float4*)&Bs[kk][tx * 4];
            const float ar[8] = {a4lo.x, a4lo.y, a4lo.z, a4lo.w,
                                 a4hi.x, a4hi.y, a4hi.z, a4hi.w};
            const float br[4] = {b4.x, b4.y, b4.z, b4.w};
#pragma unroll
            for (int i = 0; i < 8; ++i)
#pragma unroll
                for (int jj = 0; jj < 4; ++jj)
                    acc[i][jj] = fmaf(ar[i], br[jj], acc[i][jj]);
        }
    }

    const int g0 = n0 + tx * 4;
    float4 bz;
    float* dst;
    int stride, col;
    if (g0 < 512) { bz = *(const float4*)&kb[g0];       dst = kwbuf; stride = 512; col = g0; }
    else          { bz = *(const float4*)&vb[g0 - 512]; dst = vbuf;  stride = 256; col = g0 - 512; }
#pragma unroll
    for (int i = 0; i < 8; ++i) {
        const int row = l0 + ty * 8 + i;
        float4 o;
        o.x = acc[i][0] + bz.x;
        o.y = acc[i][1] + bz.y;
        o.z = acc[i][2] + bz.z;
        o.w = acc[i][3] + bz.w;
        *(float4*)&dst[row * stride + col] = o;
    }
}

// ================= K2: fused norm + small-proj + adaptive local conv =================
// Attn/denominator path bitwise == round 6. New: combined-row-weight fast path for
// stage 3 (valid when every tap with a*f != 0 satisfies pc[n]==p[n+1]; per-block
// uniform flag, slow path = round-6 loop otherwise).
__global__ void conv_fused(const float* __restrict__ x,
                           const float* __restrict__ ww, const float* __restrict__ wb,
                           const float* __restrict__ wg,
                           const float* __restrict__ ow, const float* __restrict__ ob,
                           const float* __restrict__ og,
                           const float* __restrict__ kg,
                           const float* __restrict__ kwraw, const float* __restrict__ v,
                           float* __restrict__ out) {
    const int l = blockIdx.x;
    const int tid = threadIdx.x;

    __shared__ float red[256];
    __shared__ float rs_s;
    __shared__ float kwrow[HK];
    __shared__ float wsz[H_HEADS], ofs[H_HEADS];
    __shared__ float4 tap[H_HEADS][N_OFF];      // {attn, frac, as_float(offF), as_float(offC)}
    __shared__ float2 warr[H_HEADS][N_OFF + 1]; // {combined weight, as_float(rowoff)}
    __shared__ float inv_denom[H_HEADS];
    __shared__ int okflag;

    if (tid == 0) okflag = 1;

    // ---- Phase A: rmsnorm(512) + silu (bitwise == round 6) ----
    {
        const int j = tid;
        const float* row = kwraw + l * HK;
        const float z0 = row[j];
        const float z1 = row[j + 256];
        red[j] = z0 * z0 + z1 * z1;
        __syncthreads();
        for (int s = 128; s > 0; s >>= 1) {
            if (j < s) red[j] += red[j + s];
            __syncthreads();
        }
        if (j == 0) rs_s = rsqrtf(red[0] / (float)HK + 1e-6f);
        __syncthreads();
        const float rs = rs_s;
        const float n0v = kg[j] * z0 * rs;
        const float n1v = kg[j + 256] * z1 * rs;
        kwrow[j]       = n0v * sigmoidf_(n0v);
        kwrow[j + 256] = n1v * sigmoidf_(n1v);
    }

    // ---- Phase B: small projections (wave 0); 8-lane parallel tail (bitwise == round 6) ----
    if (tid < 64) {
        const int lane = tid;
        const float* xr = x + l * C_DIM;
        float accw[H_HEADS], acco[H_HEADS];
#pragma unroll
        for (int h = 0; h < H_HEADS; ++h) { accw[h] = 0.0f; acco[h] = 0.0f; }
#pragma unroll
        for (int i = 0; i < C_DIM / 64; ++i) {
            const int c = lane + i * 64;
            const float xv = xr[c];
            const float* wwc = ww + c * H_HEADS;
            const float* owc = ow + c * H_HEADS;
#pragma unroll
            for (int h = 0; h < H_HEADS; ++h) {
                accw[h] = fmaf(xv, wwc[h], accw[h]);
                acco[h] = fmaf(xv, owc[h], acco[h]);
            }
        }
#pragma unroll
        for (int off = 32; off > 0; off >>= 1) {
#pragma unroll
            for (int h = 0; h < H_HEADS; ++h) {
                accw[h] += __shfl_xor(accw[h], off);
                acco[h] += __shfl_xor(acco[h], off);
            }
        }
        if (lane < H_HEADS) {
            float zw[H_HEADS], zo[H_HEADS];
            float ssw = 0.0f, sso = 0.0f;
#pragma unroll
            for (int h = 0; h < H_HEADS; ++h) {
                zw[h] = accw[h] + wb[h];
                zo[h] = acco[h] + ob[h];
                ssw += zw[h] * zw[h];
                sso += zo[h] * zo[h];
            }
            const float rw = rsqrtf(ssw / (float)H_HEADS + 1e-6f);
            const float ro = rsqrtf(sso / (float)H_HEADS + 1e-6f);
            const float nw = wg[lane] * zw[lane] * rw;
            const float no = og[lane] * zo[lane] * ro;
            wsz[lane] = 1.0f + sigmoidf_(nw) * 63.0f;
            ofs[lane] = tanhf(no) * 64.0f;
        }
    }
    __syncthreads();

    // ---- Stage 1: attention taps (expressions bitwise == round 6) ----
    for (int t = tid; t < H_HEADS * N_OFF; t += 256) {
        const int h = t / N_OFF;
        const int n = t - h * N_OFF;
        const float ws  = wsz[h];
        const float off = ofs[h];
        const float local = (float)(n - HALF_W);
        const float neighbor = (float)l + off + local;
        const bool valid = (neighbor >= 0.0f) && (neighbor < (float)L_SEQ);
        const float nc = fminf(fmaxf(neighbor, 0.0f), (float)(L_SEQ - 1));

        const float rel = fabsf(local) / (ws * 0.5f + 1e-6f);
        const float mask = sigmoidf_(5.0f * (1.0f - rel)) * (valid ? 1.0f : 0.0f);

        const float kidx = fminf(rel, 1.0f) * (float)(K_MAX - 1);
        int ifl = (int)kidx;
        ifl = min(ifl, K_MAX - 2);
        const float wce = kidx - (float)ifl;
        const float kf = kwrow[h * K_MAX + ifl];
        const float kc = kwrow[h * K_MAX + ifl + 1];
        const float attnv = (kf * (1.0f - wce) + kc * wce) * mask;

        int p = (int)floorf(nc);
        p = min(max(p, 0), L_SEQ - 1);
        const int pc = min(p + 1, L_SEQ - 1);
        const float fr = nc - (float)p;

        float4 tv;
        tv.x = attnv;
        tv.y = fr;
        tv.z = __int_as_float(p * C_DIM + h * D_HEAD);
        tv.w = __int_as_float(pc * C_DIM + h * D_HEAD);
        tap[h][n] = tv;
    }
    __syncthreads();

    // ---- Stage 1.5: build combined row weights + check fast-path validity ----
    // w[m] = a[m]*(1-f[m]) + a[m-1]*f[m-1]; row[m] = offF[m] (m<65), offC[64] (m==65).
    // Valid iff every tap n<64 with a*f != 0 has offC[n] == offF[n+1].
    for (int t = tid; t < H_HEADS * (N_OFF + 1); t += 256) {
        const int h = t / (N_OFF + 1);
        const int m = t - h * (N_OFF + 1);
        float w, rowf;
        if (m == 0) {
            const float4 cur = tap[h][0];
            w = cur.x * (1.0f - cur.y);
            rowf = cur.z;
        } else {
            const float4 prev = tap[h][m - 1];
            const float wc = prev.x * prev.y;
            if (m < N_OFF) {
                const float4 cur = tap[h][m];
                w = cur.x * (1.0f - cur.y) + wc;
                rowf = cur.z;
                if (wc != 0.0f && __float_as_int(prev.w) != __float_as_int(cur.z))
                    okflag = 0;   // benign race: all writers store 0
            } else {
                w = wc;
                rowf = prev.w;
            }
        }
        warr[h][m] = make_float2(w, rowf);
    }

    // ---- Stage 2: per-head denominators (serial n order, bitwise == round 6) ----
    if (tid < H_HEADS) {
        float s = 0.0f;
        for (int n = 0; n < N_OFF; ++n) s += tap[tid][n].x;
        inv_denom[tid] = 1.0f / (s + 1e-6f);
    }
    __syncthreads();

    // ---- Stage 3: gather & accumulate ----
    const int h = tid >> 5;
    const int d = tid & 31;
    float acc = 0.0f;
    if (okflag) {
#pragma unroll 6
        for (int m = 0; m < N_OFF + 1; ++m) {
            const float2 t2 = warr[h][m];
            acc = fmaf(t2.x, v[__float_as_int(t2.y) + d], acc);
        }
    } else {
#pragma unroll 5
        for (int n = 0; n < N_OFF; ++n) {
            const float4 t4 = tap[h][n];
            const int bf = __float_as_int(t4.z);
            const int bc = __float_as_int(t4.w);
            const float vf = v[bf + d];
            const float vc = v[bc + d];
            acc = fmaf(t4.x, fmaf(t4.y, vc - vf, vf), acc);
        }
    }
    out[l * C_DIM + h * D_HEAD + d] = acc * inv_denom[h];
}

// ================= K3: out projection GEMM + silu =================
// BM=64, BN=64, BK=16, TM=4, TN=4, 256 threads, grid (4, 64) = 256 blocks (1/CU).
__global__ void out_gemm(const float* __restrict__ A, const float* __restrict__ W,
                         float* __restrict__ out) {
    __shared__ float As[16][68];
    __shared__ float Bs[16][68];

    const int tid = threadIdx.x;
    const int tx = tid & 15;
    const int ty = tid >> 4;
    const int l0 = blockIdx.y * 64;
    const int n0 = blockIdx.x * 64;

    const int am = tid >> 2;
    const int ak = (tid & 3) * 4;
    const int bk = tid >> 4;
    const int bn = (tid & 15) * 4;

    float acc[4][4];
#pragma unroll
    for (int i = 0; i < 4; ++i)
#pragma unroll
        for (int jj = 0; jj < 4; ++jj) acc[i][jj] = 0.0f;

    float4 av = *(const float4*)&A[(l0 + am) * C_DIM + ak];
    float4 bv = *(const float4*)&W[bk * C_DIM + n0 + bn];

    for (int k0 = 0; k0 < C_DIM; k0 += 16) {
        __syncthreads();
        As[ak + 0][am] = av.x;
        As[ak + 1][am] = av.y;
        As[ak + 2][am] = av.z;
        As[ak + 3][am] = av.w;
        *(float4*)&Bs[bk][bn] = bv;
        __syncthreads();
        if (k0 + 16 < C_DIM) {
            av = *(const float4*)&A[(l0 + am) * C_DIM + (k0 + 16) + ak];
            bv = *(const float4*)&W[(k0 + 16 + bk) * C_DIM + n0 + bn];
        }
#pragma unroll
        for (int kk = 0; kk < 16; ++kk) {
            const float4 a4 = *(const float4*)&As[kk][ty * 4];
            const float4 b4 = *(const float4*)&Bs[kk][tx * 4];
            const float ar[4] = {a4.x, a4.y, a4.z, a4.w};
            const float br[4] = {b4.x, b4.y, b4.z, b4.w};
#pragma unroll
            for (int i = 0; i < 4; ++i)
#pragma unroll
                for (int jj = 0; jj < 4; ++jj)
                    acc[i][jj] = fmaf(ar[i], br[jj], acc[i][jj]);
        }
    }

    const int g0 = n0 + tx * 4;
#pragma unroll
    for (int i = 0; i < 4; ++i) {
        const int row = l0 + ty * 4 + i;
        float4 o;
        o.x = acc[i][0] * sigmoidf_(acc[i][0]);
        o.y = acc[i][1] * sigmoidf_(acc[i][1]);
        o.z = acc[i][2] * sigmoidf_(acc[i][2]);
        o.w = acc[i][3] * sigmoidf_(acc[i][3]);
        *(float4*)&out[row * C_DIM + g0] = o;
    }
}

extern "C" void kernel_launch(void* const* d_in, const int* in_sizes, int n_in,
                              void* d_out, int out_size, void* d_ws, size_t ws_size,
                              hipStream_t stream) {
    const float* x    = (const float*)d_in[0];
    const float* ww   = (const float*)d_in[1];
    const float* wb   = (const float*)d_in[2];
    const float* wg   = (const float*)d_in[3];
    const float* ow   = (const float*)d_in[4];
    const float* ob   = (const float*)d_in[5];
    const float* og   = (const float*)d_in[6];
    const float* kw_w = (const float*)d_in[7];
    const float* kb   = (const float*)d_in[8];
    const float* kg   = (const float*)d_in[9];
    const float* vw   = (const float*)d_in[10];
    const float* vb   = (const float*)d_in[11];
    const float* outw = (const float*)d_in[12];
    float* y = (float*)d_out;

    float* ws_f    = (float*)d_ws;
    float* kwbuf   = ws_f;                       // 4096*512 (raw z+bias)
    float* vbuf    = kwbuf + L_SEQ * HK;         // 4096*256
    float* convbuf = vbuf + L_SEQ * C_DIM;       // 4096*256

    proj_gemm<<<dim3(12, L_SEQ / 128), 256, 0, stream>>>(x, kw_w, vw, kb, vb, kwbuf, vbuf);
    conv_fused<<<L_SEQ, 256, 0, stream>>>(x, ww, wb, wg, ow, ob, og, kg, kwbuf, vbuf, convbuf);
    out_gemm<<<dim3(C_DIM / 64, L_SEQ / 64), 256, 0, stream>>>(convbuf, outw, y);
}